// Round 5
// baseline (395.856 us; speedup 1.0000x reference)
//
#include <hip/hip_runtime.h>
#include <math.h>

typedef __attribute__((ext_vector_type(8))) short short8;
typedef __attribute__((ext_vector_type(4))) float floatx4;

namespace {
constexpr int kB = 2, kN = 2048, kDIM = 1536, kH = 8, kDK = 64, kDV = 192;
constexpr int kHDV = kH * kDV;   // 1536
constexpr float kScale = 0.125f; // DK^-0.5
constexpr float kLog2e = 1.44269504088896340736f;
}

__device__ __forceinline__ unsigned short f2b(float f) {
    union { float f; unsigned u; } v; v.f = f;
    unsigned r = (v.u + 0x7FFFu + ((v.u >> 16) & 1u)) >> 16;
    return (unsigned short)r;
}

// ---------------------------------------------------------------------------
// convert fp32 weight [1536][Ncols] -> bf16 transposed [Ncols rows][1536]
// ---------------------------------------------------------------------------
__global__ __launch_bounds__(256) void conv_w(
    const float* __restrict__ src, unsigned short* __restrict__ dst, int Ncols)
{
    __shared__ float Ts[32][33];
    const int tx = threadIdx.x & 31, ty = threadIdx.x >> 5;
    const int k0 = blockIdx.x * 32, n0 = blockIdx.y * 32;
#pragma unroll
    for (int p = 0; p < 4; ++p)
        Ts[ty + p * 8][tx] = src[(size_t)(k0 + ty + p * 8) * Ncols + n0 + tx];
    __syncthreads();
#pragma unroll
    for (int p = 0; p < 4; ++p)
        dst[(size_t)(n0 + ty + p * 8) * kDIM + k0 + tx] = f2b(Ts[tx][ty + p * 8]);
}

// ---------------------------------------------------------------------------
// x fp32 -> bf16 (elementwise), 4 elems/thread
// ---------------------------------------------------------------------------
__global__ __launch_bounds__(256) void conv_x(
    const float* __restrict__ x, unsigned short* __restrict__ xb)
{
    int idx = blockIdx.x * 256 + threadIdx.x;
    float4 v = *(const float4*)&x[(size_t)idx * 4];
    ushort4 o; o.x = f2b(v.x); o.y = f2b(v.y); o.z = f2b(v.z); o.w = f2b(v.w);
    *(ushort4*)&xb[(size_t)idx * 4] = o;
}

// ---------------------------------------------------------------------------
// wcm_t[h*1536+dim] = log2e * scale * sum_d Wq[dim][h*64+d]*Wrel[h*64+d]
// wcm_t[12288+h]    = log2e * rpb[h].Wrel[h]
// (log2e fold: softmax runs in exp2 domain)
// ---------------------------------------------------------------------------
__global__ __launch_bounds__(256) void wcm_pre(
    const float* __restrict__ Wq, const float* __restrict__ Wrel,
    const float* __restrict__ rpb, float* __restrict__ wcm)
{
    int gid = blockIdx.x * 256 + threadIdx.x;
    if (gid < 12288) {
        int dim = gid >> 3, h = gid & 7;
        float s = 0.f;
#pragma unroll 8
        for (int d = 0; d < 64; ++d)
            s += Wq[(size_t)dim * 512 + h * 64 + d] * Wrel[h * 64 + d];
        wcm[h * kDIM + dim] = s * kScale * kLog2e;
    } else if (gid < 12296) {
        int h = gid - 12288;
        float s = 0.f;
#pragma unroll 8
        for (int d = 0; d < 64; ++d) s += rpb[h * 64 + d] * Wrel[h * 64 + d];
        wcm[12288 + h] = s * kLog2e;
    }
}

// ---------------------------------------------------------------------------
// c[b,h,i] = x[row].wcm_t[h] + const[h]  — one wave per x-row, fp32 exact.
// ---------------------------------------------------------------------------
__global__ __launch_bounds__(256) void c_gemm(
    const float* __restrict__ x, const float* __restrict__ wcm,
    float* __restrict__ cw)
{
    const int row  = blockIdx.x * 4 + (threadIdx.x >> 6);
    const int lane = threadIdx.x & 63;
    const float* xr = x + (size_t)row * kDIM;

    float4 xv[6];
#pragma unroll
    for (int c = 0; c < 6; ++c)
        xv[c] = *(const float4*)&xr[c * 256 + lane * 4];

    float acc[8];
#pragma unroll
    for (int h = 0; h < 8; ++h) {
        const float* wr = wcm + h * kDIM;
        float a = 0.f;
#pragma unroll
        for (int c = 0; c < 6; ++c) {
            float4 wv = *(const float4*)&wr[c * 256 + lane * 4];
            a += xv[c].x * wv.x + xv[c].y * wv.y + xv[c].z * wv.z + xv[c].w * wv.w;
        }
        acc[h] = a;
    }
#pragma unroll
    for (int h = 0; h < 8; ++h) {
        float a = acc[h];
        a += __shfl_xor(a, 1, 64);
        a += __shfl_xor(a, 2, 64);
        a += __shfl_xor(a, 4, 64);
        a += __shfl_xor(a, 8, 64);
        a += __shfl_xor(a, 16, 64);
        a += __shfl_xor(a, 32, 64);
        acc[h] = a;
    }
    if (lane == 0) {
        const int b = row >> 11, i = row & 2047;
#pragma unroll
        for (int h = 0; h < 8; ++h)
            cw[(size_t)(b * 8 + h) * kN + i] = acc[h] + wcm[12288 + h];
    }
}

// ---------------------------------------------------------------------------
// QKV GEMM (bf16 MFMA): q written pre-scaled by kScale*log2e with rcb folded.
// ---------------------------------------------------------------------------
__global__ __launch_bounds__(256) void mm_qkv(
    const unsigned short* __restrict__ xb,   // [4096][1536] bf16
    const unsigned short* __restrict__ wt,   // [2560][1536] bf16 (B^T)
    const float* __restrict__ rcb,           // [H*DK] fp32
    unsigned short* __restrict__ qo,         // [BH][N][64]
    unsigned short* __restrict__ ko,         // [BH][N][64]
    unsigned short* __restrict__ vo)         // [BH][N][192]
{
    __shared__ unsigned short A_lds[128 * 72];
    __shared__ unsigned short B_lds[128 * 72];
    const int tid = threadIdx.x;
    const int wave = tid >> 6, lane = tid & 63, lm = lane & 15, lg = lane >> 4;
    const int bm = blockIdx.y * 128, bn = blockIdx.x * 128;
    const int mb = (wave >> 1) * 64, nb = (wave & 1) * 64;

    floatx4 acc[4][4];
#pragma unroll
    for (int i = 0; i < 4; ++i)
#pragma unroll
        for (int j = 0; j < 4; ++j)
#pragma unroll
            for (int r = 0; r < 4; ++r) acc[i][j][r] = 0.f;

    const int srow = tid >> 3, scc = (tid & 7) * 8;
    short8 ra[4], rb[4];
#pragma unroll
    for (int p = 0; p < 4; ++p) {
        ra[p] = *(const short8*)&xb[(size_t)(bm + srow + p * 32) * kDIM + scc];
        rb[p] = *(const short8*)&wt[(size_t)(bn + srow + p * 32) * kDIM + scc];
    }

    for (int kt = 0; kt < 24; ++kt) {
        __syncthreads();
#pragma unroll
        for (int p = 0; p < 4; ++p) {
            *(short8*)&A_lds[(srow + p * 32) * 72 + scc] = ra[p];
            *(short8*)&B_lds[(srow + p * 32) * 72 + scc] = rb[p];
        }
        __syncthreads();
        if (kt < 23) {
            int k0 = (kt + 1) * 64;
#pragma unroll
            for (int p = 0; p < 4; ++p) {
                ra[p] = *(const short8*)&xb[(size_t)(bm + srow + p * 32) * kDIM + k0 + scc];
                rb[p] = *(const short8*)&wt[(size_t)(bn + srow + p * 32) * kDIM + k0 + scc];
            }
        }
#pragma unroll
        for (int ks = 0; ks < 2; ++ks) {
            short8 af[4], bf[4];
#pragma unroll
            for (int mi = 0; mi < 4; ++mi)
                af[mi] = *(const short8*)&A_lds[(mb + mi * 16 + lm) * 72 + lg * 8 + 32 * ks];
#pragma unroll
            for (int ni = 0; ni < 4; ++ni)
                bf[ni] = *(const short8*)&B_lds[(nb + ni * 16 + lm) * 72 + lg * 8 + 32 * ks];
#pragma unroll
            for (int mi = 0; mi < 4; ++mi)
#pragma unroll
                for (int ni = 0; ni < 4; ++ni)
                    acc[mi][ni] = __builtin_amdgcn_mfma_f32_16x16x32_bf16(
                        af[mi], bf[ni], acc[mi][ni], 0, 0, 0);
        }
    }

#pragma unroll
    for (int mi = 0; mi < 4; ++mi)
#pragma unroll
        for (int ni = 0; ni < 4; ++ni)
#pragma unroll
            for (int r = 0; r < 4; ++r) {
                int row = bm + mb + mi * 16 + lg * 4 + r;
                int b = row >> 11, i = row & 2047;
                int col = bn + nb + ni * 16 + lm;
                float v = acc[mi][ni][r];
                if (bn < 512) {
                    int h = col >> 6, d = col & 63;
                    qo[((size_t)(b * 8 + h) * kN + i) * kDK + d] =
                        f2b((v * kScale + rcb[h * 64 + d]) * kLog2e);
                } else if (bn < 1024) {
                    int c2 = col - 512, h = c2 >> 6, d = c2 & 63;
                    ko[((size_t)(b * 8 + h) * kN + i) * kDK + d] = f2b(v);
                } else {
                    int c2 = col - 1024, h = c2 / 192, d = c2 - h * 192;
                    vo[((size_t)(b * 8 + h) * kN + i) * kDV + d] = f2b(v);
                }
            }
}

// ---------------------------------------------------------------------------
// V transpose: [bh][i][192] -> [bh][192][i]  (bf16)
// ---------------------------------------------------------------------------
__global__ __launch_bounds__(256) void vtrans(
    const unsigned short* __restrict__ vw, unsigned short* __restrict__ vt)
{
    __shared__ unsigned short Ts[32][33];
    const int tx = threadIdx.x & 31, ty = threadIdx.x >> 5;
    const int i0 = blockIdx.x * 32, d0 = blockIdx.y * 32, bh = blockIdx.z;
#pragma unroll
    for (int p = 0; p < 4; ++p)
        Ts[ty + p * 8][tx] = vw[((size_t)bh * kN + i0 + ty + p * 8) * kDV + d0 + tx];
    __syncthreads();
#pragma unroll
    for (int p = 0; p < 4; ++p)
        vt[((size_t)bh * kDV + d0 + ty + p * 8) * kN + i0 + tx] = Ts[tx][ty + p * 8];
}

// ---------------------------------------------------------------------------
// Flash attention, MFMA, wave-split PV.
// QK^T: wave w owns q-rows [w*16, w*16+16); P block-shared [64][68].
// PV: wave w computes O[all 64 rows][cols w*48..w*48+48) -> V-frag reads 6/wave.
// Softmax in exp2 domain (inputs pre-scaled by log2e). XCD-swizzled grid.
// ---------------------------------------------------------------------------
__global__ __launch_bounds__(256) void flash_attn(
    const unsigned short* __restrict__ q,    // [BH][N][64] bf16 (log2e*(s*q)+rcb folded)
    const unsigned short* __restrict__ k,    // [BH][N][64] bf16
    const unsigned short* __restrict__ vt,   // [BH][192][N] bf16 (transposed)
    const float* __restrict__ crel,          // [BH][N] fp32 (log2e folded)
    unsigned short* __restrict__ ao)         // [B*N][1536] bf16
{
    __shared__ unsigned short K_lds[64 * 72];    //  9216 B
    __shared__ unsigned short V_lds[192 * 72];   // 27648 B
    __shared__ unsigned short P_lds[64 * 68];    //  8704 B (stride 68: conflict-free)
    __shared__ float cs[64];
    __shared__ float alpha_s[64];
    __shared__ float l_s[64];

    const int tid = threadIdx.x;
    const int wave = tid >> 6, lane = tid & 63, lm = lane & 15, lg = lane >> 4;
    // XCD swizzle: 2 bh per XCD (K/V working set 2MB fits 4MB XCD-L2)
    const int id = blockIdx.x;
    const int rem = id >> 3;
    const int bh = (id & 7) * 2 + (rem >> 5);
    const int i0 = (rem & 31) * 64;

    short8 qA[2];
    {
        const size_t qb = ((size_t)bh * kN + i0 + wave * 16 + lm) * kDK + lg * 8;
        qA[0] = *(const short8*)&q[qb];
        qA[1] = *(const short8*)&q[qb + 32];
    }
    if (tid < 64) cs[tid] = crel[(size_t)bh * kN + i0 + tid];

    floatx4 o4[3][4];   // [nd][g]: rows g*16+lg*4+r, cols wave*48+nd*16+lm
#pragma unroll
    for (int nd = 0; nd < 3; ++nd)
#pragma unroll
        for (int g = 0; g < 4; ++g)
#pragma unroll
            for (int r = 0; r < 4; ++r) o4[nd][g][r] = 0.f;
    float m_[4] = {-INFINITY, -INFINITY, -INFINITY, -INFINITY};
    float l_[4] = {0.f, 0.f, 0.f, 0.f};

    const unsigned short* kb = k + (size_t)bh * kN * kDK;
    const unsigned short* vb = vt + (size_t)bh * kDV * kN;

    for (int t = 0; t < 32; ++t) {
        const int j0 = t * 64;
        __syncthreads();   // (1) prev tile fully consumed
#pragma unroll
        for (int p = 0; p < 2; ++p) {
            int c = tid + p * 256;
            int row = c >> 3, cc = (c & 7) * 8;
            *(short8*)&K_lds[row * 72 + cc] =
                *(const short8*)&kb[(size_t)(j0 + row) * kDK + cc];
        }
#pragma unroll
        for (int p = 0; p < 6; ++p) {
            int c = tid + p * 256;
            int row = c >> 3, cc = (c & 7) * 8;
            *(short8*)&V_lds[row * 72 + cc] =
                *(const short8*)&vb[(size_t)row * kN + j0 + cc];
        }
        __syncthreads();   // (2) K/V staged

        // S = Q K^T for this wave's 16 q-rows
        floatx4 s4[4];
#pragma unroll
        for (int st = 0; st < 4; ++st) {
#pragma unroll
            for (int r = 0; r < 4; ++r) s4[st][r] = 0.f;
#pragma unroll
            for (int ks = 0; ks < 2; ++ks) {
                short8 kf = *(const short8*)&K_lds[(st * 16 + lm) * 72 + lg * 8 + 32 * ks];
                s4[st] = __builtin_amdgcn_mfma_f32_16x16x32_bf16(qA[ks], kf, s4[st], 0, 0, 0);
            }
        }

        // rel term + online softmax (exp2 domain); P + alpha -> block-shared LDS
#pragma unroll
        for (int r = 0; r < 4; ++r) {
            const int row = wave * 16 + lg * 4 + r;
            const float ci = cs[row];
            const float gi = (float)(i0 + row);
            float sv[4];
#pragma unroll
            for (int st = 0; st < 4; ++st)
                sv[st] = s4[st][r] + ((float)(j0 + st * 16 + lm) - gi) * ci;
            float mx = fmaxf(fmaxf(sv[0], sv[1]), fmaxf(sv[2], sv[3]));
            mx = fmaxf(mx, __shfl_xor(mx, 1, 64));
            mx = fmaxf(mx, __shfl_xor(mx, 2, 64));
            mx = fmaxf(mx, __shfl_xor(mx, 4, 64));
            mx = fmaxf(mx, __shfl_xor(mx, 8, 64));
            float mnew = fmaxf(m_[r], mx);
            float alpha = exp2f(m_[r] - mnew);
            m_[r] = mnew;
            float ts = 0.f;
#pragma unroll
            for (int st = 0; st < 4; ++st) {
                float pv = exp2f(sv[st] - mnew);
                ts += pv;
                P_lds[row * 68 + st * 16 + lm] = f2b(pv);
            }
            ts += __shfl_xor(ts, 1, 64);
            ts += __shfl_xor(ts, 2, 64);
            ts += __shfl_xor(ts, 4, 64);
            ts += __shfl_xor(ts, 8, 64);
            l_[r] = l_[r] * alpha + ts;
            if (lm == 0) alpha_s[row] = alpha;
        }
        __syncthreads();   // (3) P + alpha visible block-wide

        // rescale O with block alphas
        floatx4 al[4];
#pragma unroll
        for (int g = 0; g < 4; ++g)
            al[g] = *(const floatx4*)&alpha_s[g * 16 + lg * 4];
#pragma unroll
        for (int nd = 0; nd < 3; ++nd)
#pragma unroll
            for (int g = 0; g < 4; ++g) o4[nd][g] *= al[g];

        // O += P V on this wave's 48-col slice
#pragma unroll
        for (int ks = 0; ks < 2; ++ks) {
            short8 pa[4];
#pragma unroll
            for (int g = 0; g < 4; ++g)
                pa[g] = *(const short8*)&P_lds[(g * 16 + lm) * 68 + lg * 8 + 32 * ks];
#pragma unroll
            for (int nd = 0; nd < 3; ++nd) {
                short8 vf = *(const short8*)&V_lds[(wave * 48 + nd * 16 + lm) * 72 + lg * 8 + 32 * ks];
#pragma unroll
                for (int g = 0; g < 4; ++g)
                    o4[nd][g] = __builtin_amdgcn_mfma_f32_16x16x32_bf16(pa[g], vf, o4[nd][g], 0, 0, 0);
            }
        }
    }

    // publish l, then normalize + write
    if (lm == 0) {
#pragma unroll
        for (int r = 0; r < 4; ++r) l_s[wave * 16 + lg * 4 + r] = l_[r];
    }
    __syncthreads();
    floatx4 lv[4];
#pragma unroll
    for (int g = 0; g < 4; ++g)
        lv[g] = *(const floatx4*)&l_s[g * 16 + lg * 4];

    const int b = bh >> 3, h = bh & 7;
#pragma unroll
    for (int g = 0; g < 4; ++g)
#pragma unroll
        for (int r = 0; r < 4; ++r) {
            float inv = 1.f / lv[g][r];
            size_t rowbase = ((size_t)b * kN + i0 + g * 16 + lg * 4 + r) * (size_t)kHDV
                             + h * kDV + wave * 48;
#pragma unroll
            for (int nd = 0; nd < 3; ++nd)
                ao[rowbase + nd * 16 + lm] = f2b(o4[nd][g][r] * inv);
        }
}

// ---------------------------------------------------------------------------
// out = aw(bf16) @ Wo + bo  (MFMA), fp32 out
// ---------------------------------------------------------------------------
__global__ __launch_bounds__(256) void mm_out(
    const unsigned short* __restrict__ aw,   // [4096][1536] bf16
    const unsigned short* __restrict__ wot,  // [1536][1536] bf16 (B^T)
    const float* __restrict__ bias,
    float* __restrict__ out)                 // [4096][1536] fp32
{
    __shared__ unsigned short A_lds[128 * 72];
    __shared__ unsigned short B_lds[128 * 72];
    const int tid = threadIdx.x;
    const int wave = tid >> 6, lane = tid & 63, lm = lane & 15, lg = lane >> 4;
    const int bm = blockIdx.y * 128, bn = blockIdx.x * 128;
    const int mb = (wave >> 1) * 64, nb = (wave & 1) * 64;

    floatx4 acc[4][4];
#pragma unroll
    for (int i = 0; i < 4; ++i)
#pragma unroll
        for (int j = 0; j < 4; ++j)
#pragma unroll
            for (int r = 0; r < 4; ++r) acc[i][j][r] = 0.f;

    const int srow = tid >> 3, scc = (tid & 7) * 8;
    short8 ra[4], rb[4];
#pragma unroll
    for (int p = 0; p < 4; ++p) {
        ra[p] = *(const short8*)&aw[(size_t)(bm + srow + p * 32) * kDIM + scc];
        rb[p] = *(const short8*)&wot[(size_t)(bn + srow + p * 32) * kDIM + scc];
    }

    for (int kt = 0; kt < 24; ++kt) {
        __syncthreads();
#pragma unroll
        for (int p = 0; p < 4; ++p) {
            *(short8*)&A_lds[(srow + p * 32) * 72 + scc] = ra[p];
            *(short8*)&B_lds[(srow + p * 32) * 72 + scc] = rb[p];
        }
        __syncthreads();
        if (kt < 23) {
            int k0 = (kt + 1) * 64;
#pragma unroll
            for (int p = 0; p < 4; ++p) {
                ra[p] = *(const short8*)&aw[(size_t)(bm + srow + p * 32) * kDIM + k0 + scc];
                rb[p] = *(const short8*)&wot[(size_t)(bn + srow + p * 32) * kDIM + k0 + scc];
            }
        }
#pragma unroll
        for (int ks = 0; ks < 2; ++ks) {
            short8 af[4], bf[4];
#pragma unroll
            for (int mi = 0; mi < 4; ++mi)
                af[mi] = *(const short8*)&A_lds[(mb + mi * 16 + lm) * 72 + lg * 8 + 32 * ks];
#pragma unroll
            for (int ni = 0; ni < 4; ++ni)
                bf[ni] = *(const short8*)&B_lds[(nb + ni * 16 + lm) * 72 + lg * 8 + 32 * ks];
#pragma unroll
            for (int mi = 0; mi < 4; ++mi)
#pragma unroll
                for (int ni = 0; ni < 4; ++ni)
                    acc[mi][ni] = __builtin_amdgcn_mfma_f32_16x16x32_bf16(
                        af[mi], bf[ni], acc[mi][ni], 0, 0, 0);
        }
    }

#pragma unroll
    for (int mi = 0; mi < 4; ++mi)
#pragma unroll
        for (int ni = 0; ni < 4; ++ni)
#pragma unroll
            for (int r = 0; r < 4; ++r) {
                int row = bm + mb + mi * 16 + lg * 4 + r;
                int col = bn + nb + ni * 16 + lm;
                out[(size_t)row * kDIM + col] = acc[mi][ni][r] + bias[col];
            }
}

// ---------------------------------------------------------------------------
extern "C" void kernel_launch(void* const* d_in, const int* in_sizes, int n_in,
                              void* d_out, int out_size, void* d_ws, size_t ws_size,
                              hipStream_t stream)
{
    const float* x    = (const float*)d_in[0];
    const float* Wq   = (const float*)d_in[1];
    const float* Wk   = (const float*)d_in[2];
    const float* Wv   = (const float*)d_in[3];
    const float* Wrel = (const float*)d_in[4];
    const float* Wo   = (const float*)d_in[5];
    const float* bo   = (const float*)d_in[6];
    const float* rcb  = (const float*)d_in[7];
    const float* rpb  = (const float*)d_in[8];
    float* out = (float*)d_out;

    char* w = (char*)d_ws;
    unsigned short* xb  = (unsigned short*)(w);              // 12,582,912 B (later: vt)
    unsigned short* wt  = (unsigned short*)(w + 12582912);   //  7,864,320 B (later: Wot)
    unsigned short* qw  = (unsigned short*)(w + 20447232);   //  4,194,304 B
    unsigned short* kw  = (unsigned short*)(w + 24641536);   //  4,194,304 B
    unsigned short* vw  = (unsigned short*)(w + 28835840);   // 12,582,912 B (later: aw)
    float*          cw  = (float*)(w + 41418752);            //    131,072 B
    float*          wcm = (float*)(w + 41549824);            //     49,184 B
    unsigned short* vtp = xb;
    unsigned short* awp = vw;
    unsigned short* wot = wt;

    { dim3 g(48, 16);  conv_w<<<g, 256, 0, stream>>>(Wq, wt,               512); }
    { dim3 g(48, 16);  conv_w<<<g, 256, 0, stream>>>(Wk, wt + 512  * 1536, 512); }
    { dim3 g(48, 48);  conv_w<<<g, 256, 0, stream>>>(Wv, wt + 1024 * 1536, 1536); }
    conv_x<<<6144, 256, 0, stream>>>(x, xb);
    wcm_pre<<<49, 256, 0, stream>>>(Wq, Wrel, rpb, wcm);
    c_gemm<<<1024, 256, 0, stream>>>(x, wcm, cw);

    { dim3 g(20, 32); mm_qkv<<<g, 256, 0, stream>>>(xb, wt, rcb, qw, kw, vw); }

    { dim3 g(48, 48); conv_w<<<g, 256, 0, stream>>>(Wo, wot, 1536); }
    { dim3 g(64, 6, 16); vtrans<<<g, 256, 0, stream>>>(vw, vtp); }

    flash_attn<<<512, 256, 0, stream>>>(qw, kw, vtp, cw, awp);

    { dim3 g(12, 32); mm_out<<<g, 256, 0, stream>>>(awp, wot, bo, out); }
}

// Round 6
// 339.384 us; speedup vs baseline: 1.1664x; 1.1664x over previous
//
#include <hip/hip_runtime.h>
#include <math.h>

typedef __attribute__((ext_vector_type(8))) short short8;
typedef __attribute__((ext_vector_type(4))) float floatx4;

namespace {
constexpr int kB = 2, kN = 2048, kDIM = 1536, kH = 8, kDK = 64, kDV = 192;
constexpr int kHDV = kH * kDV;   // 1536
constexpr float kScale = 0.125f; // DK^-0.5
constexpr float kLog2e = 1.44269504088896340736f;
}

__device__ __forceinline__ unsigned short f2b(float f) {
    union { float f; unsigned u; } v; v.f = f;
    unsigned r = (v.u + 0x7FFFu + ((v.u >> 16) & 1u)) >> 16;
    return (unsigned short)r;
}

// ---------------------------------------------------------------------------
// convert fp32 weight [1536][Ncols] -> bf16 transposed [Ncols rows][1536]
// ---------------------------------------------------------------------------
__global__ __launch_bounds__(256) void conv_w(
    const float* __restrict__ src, unsigned short* __restrict__ dst, int Ncols)
{
    __shared__ float Ts[32][33];
    const int tx = threadIdx.x & 31, ty = threadIdx.x >> 5;
    const int k0 = blockIdx.x * 32, n0 = blockIdx.y * 32;
#pragma unroll
    for (int p = 0; p < 4; ++p)
        Ts[ty + p * 8][tx] = src[(size_t)(k0 + ty + p * 8) * Ncols + n0 + tx];
    __syncthreads();
#pragma unroll
    for (int p = 0; p < 4; ++p)
        dst[(size_t)(n0 + ty + p * 8) * kDIM + k0 + tx] = f2b(Ts[tx][ty + p * 8]);
}

// ---------------------------------------------------------------------------
// x fp32 -> bf16 (elementwise), 4 elems/thread
// ---------------------------------------------------------------------------
__global__ __launch_bounds__(256) void conv_x(
    const float* __restrict__ x, unsigned short* __restrict__ xb)
{
    int idx = blockIdx.x * 256 + threadIdx.x;
    float4 v = *(const float4*)&x[(size_t)idx * 4];
    ushort4 o; o.x = f2b(v.x); o.y = f2b(v.y); o.z = f2b(v.z); o.w = f2b(v.w);
    *(ushort4*)&xb[(size_t)idx * 4] = o;
}

// ---------------------------------------------------------------------------
// wcm_t[h*1536+dim] = log2e * scale * sum_d Wq[dim][h*64+d]*Wrel[h*64+d]
// wcm_t[12288+h]    = log2e * rpb[h].Wrel[h]
// ---------------------------------------------------------------------------
__global__ __launch_bounds__(256) void wcm_pre(
    const float* __restrict__ Wq, const float* __restrict__ Wrel,
    const float* __restrict__ rpb, float* __restrict__ wcm)
{
    int gid = blockIdx.x * 256 + threadIdx.x;
    if (gid < 12288) {
        int dim = gid >> 3, h = gid & 7;
        float s = 0.f;
#pragma unroll 8
        for (int d = 0; d < 64; ++d)
            s += Wq[(size_t)dim * 512 + h * 64 + d] * Wrel[h * 64 + d];
        wcm[h * kDIM + dim] = s * kScale * kLog2e;
    } else if (gid < 12296) {
        int h = gid - 12288;
        float s = 0.f;
#pragma unroll 8
        for (int d = 0; d < 64; ++d) s += rpb[h * 64 + d] * Wrel[h * 64 + d];
        wcm[12288 + h] = s * kLog2e;
    }
}

// ---------------------------------------------------------------------------
// c[b,h,i] = x[row].wcm_t[h] + const[h]  — one wave per x-row, fp32 exact.
// ---------------------------------------------------------------------------
__global__ __launch_bounds__(256) void c_gemm(
    const float* __restrict__ x, const float* __restrict__ wcm,
    float* __restrict__ cw)
{
    const int row  = blockIdx.x * 4 + (threadIdx.x >> 6);
    const int lane = threadIdx.x & 63;
    const float* xr = x + (size_t)row * kDIM;

    float4 xv[6];
#pragma unroll
    for (int c = 0; c < 6; ++c)
        xv[c] = *(const float4*)&xr[c * 256 + lane * 4];

    float acc[8];
#pragma unroll
    for (int h = 0; h < 8; ++h) {
        const float* wr = wcm + h * kDIM;
        float a = 0.f;
#pragma unroll
        for (int c = 0; c < 6; ++c) {
            float4 wv = *(const float4*)&wr[c * 256 + lane * 4];
            a += xv[c].x * wv.x + xv[c].y * wv.y + xv[c].z * wv.z + xv[c].w * wv.w;
        }
        acc[h] = a;
    }
#pragma unroll
    for (int h = 0; h < 8; ++h) {
        float a = acc[h];
        a += __shfl_xor(a, 1, 64);
        a += __shfl_xor(a, 2, 64);
        a += __shfl_xor(a, 4, 64);
        a += __shfl_xor(a, 8, 64);
        a += __shfl_xor(a, 16, 64);
        a += __shfl_xor(a, 32, 64);
        acc[h] = a;
    }
    if (lane == 0) {
        const int b = row >> 11, i = row & 2047;
#pragma unroll
        for (int h = 0; h < 8; ++h)
            cw[(size_t)(b * 8 + h) * kN + i] = acc[h] + wcm[12288 + h];
    }
}

// ---------------------------------------------------------------------------
// QKV GEMM (bf16 MFMA): q written pre-scaled by kScale*log2e with rcb folded.
// ---------------------------------------------------------------------------
__global__ __launch_bounds__(256) void mm_qkv(
    const unsigned short* __restrict__ xb,   // [4096][1536] bf16
    const unsigned short* __restrict__ wt,   // [2560][1536] bf16 (B^T)
    const float* __restrict__ rcb,           // [H*DK] fp32
    unsigned short* __restrict__ qo,         // [BH][N][64]
    unsigned short* __restrict__ ko,         // [BH][N][64]
    unsigned short* __restrict__ vo)         // [BH][N][192]
{
    __shared__ unsigned short A_lds[128 * 72];
    __shared__ unsigned short B_lds[128 * 72];
    const int tid = threadIdx.x;
    const int wave = tid >> 6, lane = tid & 63, lm = lane & 15, lg = lane >> 4;
    const int bm = blockIdx.y * 128, bn = blockIdx.x * 128;
    const int mb = (wave >> 1) * 64, nb = (wave & 1) * 64;

    floatx4 acc[4][4];
#pragma unroll
    for (int i = 0; i < 4; ++i)
#pragma unroll
        for (int j = 0; j < 4; ++j)
#pragma unroll
            for (int r = 0; r < 4; ++r) acc[i][j][r] = 0.f;

    const int srow = tid >> 3, scc = (tid & 7) * 8;
    short8 ra[4], rb[4];
#pragma unroll
    for (int p = 0; p < 4; ++p) {
        ra[p] = *(const short8*)&xb[(size_t)(bm + srow + p * 32) * kDIM + scc];
        rb[p] = *(const short8*)&wt[(size_t)(bn + srow + p * 32) * kDIM + scc];
    }

    for (int kt = 0; kt < 24; ++kt) {
        __syncthreads();
#pragma unroll
        for (int p = 0; p < 4; ++p) {
            *(short8*)&A_lds[(srow + p * 32) * 72 + scc] = ra[p];
            *(short8*)&B_lds[(srow + p * 32) * 72 + scc] = rb[p];
        }
        __syncthreads();
        if (kt < 23) {
            int k0 = (kt + 1) * 64;
#pragma unroll
            for (int p = 0; p < 4; ++p) {
                ra[p] = *(const short8*)&xb[(size_t)(bm + srow + p * 32) * kDIM + k0 + scc];
                rb[p] = *(const short8*)&wt[(size_t)(bn + srow + p * 32) * kDIM + k0 + scc];
            }
        }
#pragma unroll
        for (int ks = 0; ks < 2; ++ks) {
            short8 af[4], bf[4];
#pragma unroll
            for (int mi = 0; mi < 4; ++mi)
                af[mi] = *(const short8*)&A_lds[(mb + mi * 16 + lm) * 72 + lg * 8 + 32 * ks];
#pragma unroll
            for (int ni = 0; ni < 4; ++ni)
                bf[ni] = *(const short8*)&B_lds[(nb + ni * 16 + lm) * 72 + lg * 8 + 32 * ks];
#pragma unroll
            for (int mi = 0; mi < 4; ++mi)
#pragma unroll
                for (int ni = 0; ni < 4; ++ni)
                    acc[mi][ni] = __builtin_amdgcn_mfma_f32_16x16x32_bf16(
                        af[mi], bf[ni], acc[mi][ni], 0, 0, 0);
        }
    }

#pragma unroll
    for (int mi = 0; mi < 4; ++mi)
#pragma unroll
        for (int ni = 0; ni < 4; ++ni)
#pragma unroll
            for (int r = 0; r < 4; ++r) {
                int row = bm + mb + mi * 16 + lg * 4 + r;
                int b = row >> 11, i = row & 2047;
                int col = bn + nb + ni * 16 + lm;
                float v = acc[mi][ni][r];
                if (bn < 512) {
                    int h = col >> 6, d = col & 63;
                    qo[((size_t)(b * 8 + h) * kN + i) * kDK + d] =
                        f2b((v * kScale + rcb[h * 64 + d]) * kLog2e);
                } else if (bn < 1024) {
                    int c2 = col - 512, h = c2 >> 6, d = c2 & 63;
                    ko[((size_t)(b * 8 + h) * kN + i) * kDK + d] = f2b(v);
                } else {
                    int c2 = col - 1024, h = c2 / 192, d = c2 - h * 192;
                    vo[((size_t)(b * 8 + h) * kN + i) * kDV + d] = f2b(v);
                }
            }
}

// ---------------------------------------------------------------------------
// V transpose: [bh][i][192] -> [bh][192][i]  (bf16)
// ---------------------------------------------------------------------------
__global__ __launch_bounds__(256) void vtrans(
    const unsigned short* __restrict__ vw, unsigned short* __restrict__ vt)
{
    __shared__ unsigned short Ts[32][33];
    const int tx = threadIdx.x & 31, ty = threadIdx.x >> 5;
    const int i0 = blockIdx.x * 32, d0 = blockIdx.y * 32, bh = blockIdx.z;
#pragma unroll
    for (int p = 0; p < 4; ++p)
        Ts[ty + p * 8][tx] = vw[((size_t)bh * kN + i0 + ty + p * 8) * kDV + d0 + tx];
    __syncthreads();
#pragma unroll
    for (int p = 0; p < 4; ++p)
        vt[((size_t)bh * kDV + d0 + ty + p * 8) * kN + i0 + tx] = Ts[tx][ty + p * 8];
}

// ---------------------------------------------------------------------------
// Flash attention, MFMA. R3 wave-private structure (2 barriers, independent
// waves) + exp2 domain + stride-68 P + XCD swizzle + T14 async-STAGE split:
// next tile's K/V loaded to regs right after the stage barrier, so HBM/L2
// latency hides under QK^T+softmax+PV; regs->LDS after barrier (1).
// ---------------------------------------------------------------------------
__global__ __launch_bounds__(256) void flash_attn(
    const unsigned short* __restrict__ q,    // [BH][N][64] bf16 (log2e*(s*q)+rcb folded)
    const unsigned short* __restrict__ k,    // [BH][N][64] bf16
    const unsigned short* __restrict__ vt,   // [BH][192][N] bf16 (transposed)
    const float* __restrict__ crel,          // [BH][N] fp32 (log2e folded)
    unsigned short* __restrict__ ao)         // [B*N][1536] bf16
{
    __shared__ unsigned short K_lds[64 * 72];    //  9216 B
    __shared__ unsigned short V_lds[192 * 72];   // 27648 B
    __shared__ unsigned short P_lds[4 * 16 * 68];//  8704 B (wave-private slabs)
    __shared__ float cs[64];

    const int tid = threadIdx.x;
    const int wave = tid >> 6, lane = tid & 63, lm = lane & 15, lg = lane >> 4;
    // XCD swizzle: 2 bh per XCD (K/V working set 2MB fits 4MB XCD-L2)
    const int id = blockIdx.x;
    const int rem = id >> 3;
    const int bh = (id & 7) * 2 + (rem >> 5);
    const int i0 = (rem & 31) * 64;

    short8 qA[2];
    {
        const size_t qb = ((size_t)bh * kN + i0 + wave * 16 + lm) * kDK + lg * 8;
        qA[0] = *(const short8*)&q[qb];
        qA[1] = *(const short8*)&q[qb + 32];
    }
    if (tid < 64) cs[tid] = crel[(size_t)bh * kN + i0 + tid];

    floatx4 o4[12];
#pragma unroll
    for (int nd = 0; nd < 12; ++nd)
#pragma unroll
        for (int r = 0; r < 4; ++r) o4[nd][r] = 0.f;
    float m_[4] = {-INFINITY, -INFINITY, -INFINITY, -INFINITY};
    float l_[4] = {0.f, 0.f, 0.f, 0.f};

    const unsigned short* kb = k + (size_t)bh * kN * kDK;
    const unsigned short* vb = vt + (size_t)bh * kDV * kN;
    const int pbase = wave * 16 * 68;
    const int srow = tid >> 3, scol = (tid & 7) * 8;

    // prologue: tile 0 -> stage registers
    short8 rk[2], rv[6];
#pragma unroll
    for (int p = 0; p < 2; ++p)
        rk[p] = *(const short8*)&kb[(size_t)(srow + p * 32) * kDK + scol];
#pragma unroll
    for (int p = 0; p < 6; ++p)
        rv[p] = *(const short8*)&vb[(size_t)(srow + p * 32) * kN + scol];

    for (int t = 0; t < 32; ++t) {
        const int j0 = t * 64;
        __syncthreads();   // (1) prev tile fully consumed
#pragma unroll
        for (int p = 0; p < 2; ++p)
            *(short8*)&K_lds[(srow + p * 32) * 72 + scol] = rk[p];
#pragma unroll
        for (int p = 0; p < 6; ++p)
            *(short8*)&V_lds[(srow + p * 32) * 72 + scol] = rv[p];
        __syncthreads();   // (2) staged
        if (t < 31) {      // issue next-tile loads; land during compute below
            const int j1 = j0 + 64;
#pragma unroll
            for (int p = 0; p < 2; ++p)
                rk[p] = *(const short8*)&kb[(size_t)(j1 + srow + p * 32) * kDK + scol];
#pragma unroll
            for (int p = 0; p < 6; ++p)
                rv[p] = *(const short8*)&vb[(size_t)(srow + p * 32) * kN + j1 + scol];
        }

        // S = Q K^T for this wave's 16 q-rows
        floatx4 s4[4];
#pragma unroll
        for (int st = 0; st < 4; ++st) {
#pragma unroll
            for (int r = 0; r < 4; ++r) s4[st][r] = 0.f;
#pragma unroll
            for (int ks = 0; ks < 2; ++ks) {
                short8 kf = *(const short8*)&K_lds[(st * 16 + lm) * 72 + lg * 8 + 32 * ks];
                s4[st] = __builtin_amdgcn_mfma_f32_16x16x32_bf16(qA[ks], kf, s4[st], 0, 0, 0);
            }
        }

        // rel term + online softmax (exp2 domain); P -> wave-private LDS
        float alpha[4];
#pragma unroll
        for (int r = 0; r < 4; ++r) {
            const int row = wave * 16 + lg * 4 + r;
            const float ci = cs[row];
            const float gi = (float)(i0 + row);
            float sv[4];
#pragma unroll
            for (int st = 0; st < 4; ++st)
                sv[st] = s4[st][r] + ((float)(j0 + st * 16 + lm) - gi) * ci;
            float mx = fmaxf(fmaxf(sv[0], sv[1]), fmaxf(sv[2], sv[3]));
            mx = fmaxf(mx, __shfl_xor(mx, 1, 64));
            mx = fmaxf(mx, __shfl_xor(mx, 2, 64));
            mx = fmaxf(mx, __shfl_xor(mx, 4, 64));
            mx = fmaxf(mx, __shfl_xor(mx, 8, 64));
            float mnew = fmaxf(m_[r], mx);
            alpha[r] = exp2f(m_[r] - mnew);
            m_[r] = mnew;
            float ts = 0.f;
#pragma unroll
            for (int st = 0; st < 4; ++st) {
                float pv = exp2f(sv[st] - mnew);
                ts += pv;
                P_lds[pbase + (lg * 4 + r) * 68 + st * 16 + lm] = f2b(pv);
            }
            ts += __shfl_xor(ts, 1, 64);
            ts += __shfl_xor(ts, 2, 64);
            ts += __shfl_xor(ts, 4, 64);
            ts += __shfl_xor(ts, 8, 64);
            l_[r] = l_[r] * alpha[r] + ts;
        }

        // rescale O
#pragma unroll
        for (int nd = 0; nd < 12; ++nd)
#pragma unroll
            for (int r = 0; r < 4; ++r) o4[nd][r] *= alpha[r];

        // O += P V : A = P (wave-private), B = V^T rows
        short8 pa[2];
        pa[0] = *(const short8*)&P_lds[pbase + lm * 68 + lg * 8];
        pa[1] = *(const short8*)&P_lds[pbase + lm * 68 + lg * 8 + 32];
#pragma unroll
        for (int nd = 0; nd < 12; ++nd) {
#pragma unroll
            for (int ks = 0; ks < 2; ++ks) {
                short8 vf = *(const short8*)&V_lds[(nd * 16 + lm) * 72 + lg * 8 + 32 * ks];
                o4[nd] = __builtin_amdgcn_mfma_f32_16x16x32_bf16(pa[ks], vf, o4[nd], 0, 0, 0);
            }
        }
    }

    // epilogue: ao[b, i, h*192 + d]
    const int b = bh >> 3, h = bh & 7;
#pragma unroll
    for (int r = 0; r < 4; ++r) {
        float inv = 1.f / l_[r];
        size_t rowbase = ((size_t)b * kN + i0 + wave * 16 + lg * 4 + r) * (size_t)kHDV
                         + h * kDV;
#pragma unroll
        for (int nd = 0; nd < 12; ++nd)
            ao[rowbase + nd * 16 + lm] = f2b(o4[nd][r] * inv);
    }
}

// ---------------------------------------------------------------------------
// out = aw(bf16) @ Wo + bo  (MFMA), fp32 out
// ---------------------------------------------------------------------------
__global__ __launch_bounds__(256) void mm_out(
    const unsigned short* __restrict__ aw,   // [4096][1536] bf16
    const unsigned short* __restrict__ wot,  // [1536][1536] bf16 (B^T)
    const float* __restrict__ bias,
    float* __restrict__ out)                 // [4096][1536] fp32
{
    __shared__ unsigned short A_lds[128 * 72];
    __shared__ unsigned short B_lds[128 * 72];
    const int tid = threadIdx.x;
    const int wave = tid >> 6, lane = tid & 63, lm = lane & 15, lg = lane >> 4;
    const int bm = blockIdx.y * 128, bn = blockIdx.x * 128;
    const int mb = (wave >> 1) * 64, nb = (wave & 1) * 64;

    floatx4 acc[4][4];
#pragma unroll
    for (int i = 0; i < 4; ++i)
#pragma unroll
        for (int j = 0; j < 4; ++j)
#pragma unroll
            for (int r = 0; r < 4; ++r) acc[i][j][r] = 0.f;

    const int srow = tid >> 3, scc = (tid & 7) * 8;
    short8 ra[4], rb[4];
#pragma unroll
    for (int p = 0; p < 4; ++p) {
        ra[p] = *(const short8*)&aw[(size_t)(bm + srow + p * 32) * kDIM + scc];
        rb[p] = *(const short8*)&wot[(size_t)(bn + srow + p * 32) * kDIM + scc];
    }

    for (int kt = 0; kt < 24; ++kt) {
        __syncthreads();
#pragma unroll
        for (int p = 0; p < 4; ++p) {
            *(short8*)&A_lds[(srow + p * 32) * 72 + scc] = ra[p];
            *(short8*)&B_lds[(srow + p * 32) * 72 + scc] = rb[p];
        }
        __syncthreads();
        if (kt < 23) {
            int k0 = (kt + 1) * 64;
#pragma unroll
            for (int p = 0; p < 4; ++p) {
                ra[p] = *(const short8*)&aw[(size_t)(bm + srow + p * 32) * kDIM + k0 + scc];
                rb[p] = *(const short8*)&wot[(size_t)(bn + srow + p * 32) * kDIM + k0 + scc];
            }
        }
#pragma unroll
        for (int ks = 0; ks < 2; ++ks) {
            short8 af[4], bf[4];
#pragma unroll
            for (int mi = 0; mi < 4; ++mi)
                af[mi] = *(const short8*)&A_lds[(mb + mi * 16 + lm) * 72 + lg * 8 + 32 * ks];
#pragma unroll
            for (int ni = 0; ni < 4; ++ni)
                bf[ni] = *(const short8*)&B_lds[(nb + ni * 16 + lm) * 72 + lg * 8 + 32 * ks];
#pragma unroll
            for (int mi = 0; mi < 4; ++mi)
#pragma unroll
                for (int ni = 0; ni < 4; ++ni)
                    acc[mi][ni] = __builtin_amdgcn_mfma_f32_16x16x32_bf16(
                        af[mi], bf[ni], acc[mi][ni], 0, 0, 0);
        }
    }

#pragma unroll
    for (int mi = 0; mi < 4; ++mi)
#pragma unroll
        for (int ni = 0; ni < 4; ++ni)
#pragma unroll
            for (int r = 0; r < 4; ++r) {
                int row = bm + mb + mi * 16 + lg * 4 + r;
                int col = bn + nb + ni * 16 + lm;
                out[(size_t)row * kDIM + col] = acc[mi][ni][r] + bias[col];
            }
}

// ---------------------------------------------------------------------------
extern "C" void kernel_launch(void* const* d_in, const int* in_sizes, int n_in,
                              void* d_out, int out_size, void* d_ws, size_t ws_size,
                              hipStream_t stream)
{
    const float* x    = (const float*)d_in[0];
    const float* Wq   = (const float*)d_in[1];
    const float* Wk   = (const float*)d_in[2];
    const float* Wv   = (const float*)d_in[3];
    const float* Wrel = (const float*)d_in[4];
    const float* Wo   = (const float*)d_in[5];
    const float* bo   = (const float*)d_in[6];
    const float* rcb  = (const float*)d_in[7];
    const float* rpb  = (const float*)d_in[8];
    float* out = (float*)d_out;

    char* w = (char*)d_ws;
    unsigned short* xb  = (unsigned short*)(w);              // 12,582,912 B (later: vt)
    unsigned short* wt  = (unsigned short*)(w + 12582912);   //  7,864,320 B (later: Wot)
    unsigned short* qw  = (unsigned short*)(w + 20447232);   //  4,194,304 B
    unsigned short* kw  = (unsigned short*)(w + 24641536);   //  4,194,304 B
    unsigned short* vw  = (unsigned short*)(w + 28835840);   // 12,582,912 B (later: aw)
    float*          cw  = (float*)(w + 41418752);            //    131,072 B
    float*          wcm = (float*)(w + 41549824);            //     49,184 B
    unsigned short* vtp = xb;
    unsigned short* awp = vw;
    unsigned short* wot = wt;

    { dim3 g(48, 16);  conv_w<<<g, 256, 0, stream>>>(Wq, wt,               512); }
    { dim3 g(48, 16);  conv_w<<<g, 256, 0, stream>>>(Wk, wt + 512  * 1536, 512); }
    { dim3 g(48, 48);  conv_w<<<g, 256, 0, stream>>>(Wv, wt + 1024 * 1536, 1536); }
    conv_x<<<6144, 256, 0, stream>>>(x, xb);
    wcm_pre<<<49, 256, 0, stream>>>(Wq, Wrel, rpb, wcm);
    c_gemm<<<1024, 256, 0, stream>>>(x, wcm, cw);

    { dim3 g(20, 32); mm_qkv<<<g, 256, 0, stream>>>(xb, wt, rcb, qw, kw, vw); }

    { dim3 g(48, 48); conv_w<<<g, 256, 0, stream>>>(Wo, wot, 1536); }
    { dim3 g(64, 6, 16); vtrans<<<g, 256, 0, stream>>>(vw, vtp); }

    flash_attn<<<512, 256, 0, stream>>>(qw, kw, vtp, cw, awp);

    { dim3 g(12, 32); mm_out<<<g, 256, 0, stream>>>(awp, wot, bo, out); }
}

// Round 7
// 329.354 us; speedup vs baseline: 1.2019x; 1.0305x over previous
//
#include <hip/hip_runtime.h>
#include <math.h>

typedef __attribute__((ext_vector_type(8))) short short8;
typedef __attribute__((ext_vector_type(4))) float floatx4;

namespace {
constexpr int kB = 2, kN = 2048, kDIM = 1536, kH = 8, kDK = 64, kDV = 192;
constexpr int kHDV = kH * kDV;   // 1536
constexpr float kScale = 0.125f; // DK^-0.5
constexpr float kLog2e = 1.44269504088896340736f;
}

__device__ __forceinline__ unsigned short f2b(float f) {
    union { float f; unsigned u; } v; v.f = f;
    unsigned r = (v.u + 0x7FFFu + ((v.u >> 16) & 1u)) >> 16;
    return (unsigned short)r;
}
// cheap round-half-up pack for P (bias immaterial: l uses same packed P)
__device__ __forceinline__ unsigned short f2b_fast(float f) {
    union { float f; unsigned u; } v; v.f = f;
    return (unsigned short)((v.u + 0x8000u) >> 16);
}

// ---------------------------------------------------------------------------
// convert fp32 weight [1536][Ncols] -> bf16 transposed [Ncols rows][1536]
// ---------------------------------------------------------------------------
__global__ __launch_bounds__(256) void conv_w(
    const float* __restrict__ src, unsigned short* __restrict__ dst, int Ncols)
{
    __shared__ float Ts[32][33];
    const int tx = threadIdx.x & 31, ty = threadIdx.x >> 5;
    const int k0 = blockIdx.x * 32, n0 = blockIdx.y * 32;
#pragma unroll
    for (int p = 0; p < 4; ++p)
        Ts[ty + p * 8][tx] = src[(size_t)(k0 + ty + p * 8) * Ncols + n0 + tx];
    __syncthreads();
#pragma unroll
    for (int p = 0; p < 4; ++p)
        dst[(size_t)(n0 + ty + p * 8) * kDIM + k0 + tx] = f2b(Ts[tx][ty + p * 8]);
}

// ---------------------------------------------------------------------------
// x fp32 -> bf16 (elementwise), 4 elems/thread
// ---------------------------------------------------------------------------
__global__ __launch_bounds__(256) void conv_x(
    const float* __restrict__ x, unsigned short* __restrict__ xb)
{
    int idx = blockIdx.x * 256 + threadIdx.x;
    float4 v = *(const float4*)&x[(size_t)idx * 4];
    ushort4 o; o.x = f2b(v.x); o.y = f2b(v.y); o.z = f2b(v.z); o.w = f2b(v.w);
    *(ushort4*)&xb[(size_t)idx * 4] = o;
}

// ---------------------------------------------------------------------------
// wcm_t[h*1536+dim] = log2e * scale * sum_d Wq[dim][h*64+d]*Wrel[h*64+d]
// wcm_t[12288+h]    = log2e * rpb[h].Wrel[h]
// ---------------------------------------------------------------------------
__global__ __launch_bounds__(256) void wcm_pre(
    const float* __restrict__ Wq, const float* __restrict__ Wrel,
    const float* __restrict__ rpb, float* __restrict__ wcm)
{
    int gid = blockIdx.x * 256 + threadIdx.x;
    if (gid < 12288) {
        int dim = gid >> 3, h = gid & 7;
        float s = 0.f;
#pragma unroll 8
        for (int d = 0; d < 64; ++d)
            s += Wq[(size_t)dim * 512 + h * 64 + d] * Wrel[h * 64 + d];
        wcm[h * kDIM + dim] = s * kScale * kLog2e;
    } else if (gid < 12296) {
        int h = gid - 12288;
        float s = 0.f;
#pragma unroll 8
        for (int d = 0; d < 64; ++d) s += rpb[h * 64 + d] * Wrel[h * 64 + d];
        wcm[12288 + h] = s * kLog2e;
    }
}

// ---------------------------------------------------------------------------
// c[b,h,i] = x[row].wcm_t[h] + const[h]  — one wave per x-row, fp32 exact.
// ---------------------------------------------------------------------------
__global__ __launch_bounds__(256) void c_gemm(
    const float* __restrict__ x, const float* __restrict__ wcm,
    float* __restrict__ cw)
{
    const int row  = blockIdx.x * 4 + (threadIdx.x >> 6);
    const int lane = threadIdx.x & 63;
    const float* xr = x + (size_t)row * kDIM;

    float4 xv[6];
#pragma unroll
    for (int c = 0; c < 6; ++c)
        xv[c] = *(const float4*)&xr[c * 256 + lane * 4];

    float acc[8];
#pragma unroll
    for (int h = 0; h < 8; ++h) {
        const float* wr = wcm + h * kDIM;
        float a = 0.f;
#pragma unroll
        for (int c = 0; c < 6; ++c) {
            float4 wv = *(const float4*)&wr[c * 256 + lane * 4];
            a += xv[c].x * wv.x + xv[c].y * wv.y + xv[c].z * wv.z + xv[c].w * wv.w;
        }
        acc[h] = a;
    }
#pragma unroll
    for (int h = 0; h < 8; ++h) {
        float a = acc[h];
        a += __shfl_xor(a, 1, 64);
        a += __shfl_xor(a, 2, 64);
        a += __shfl_xor(a, 4, 64);
        a += __shfl_xor(a, 8, 64);
        a += __shfl_xor(a, 16, 64);
        a += __shfl_xor(a, 32, 64);
        acc[h] = a;
    }
    if (lane == 0) {
        const int b = row >> 11, i = row & 2047;
#pragma unroll
        for (int h = 0; h < 8; ++h)
            cw[(size_t)(b * 8 + h) * kN + i] = acc[h] + wcm[12288 + h];
    }
}

// ---------------------------------------------------------------------------
// QKV GEMM (bf16 MFMA): q written pre-scaled by kScale*log2e with rcb folded.
// ---------------------------------------------------------------------------
__global__ __launch_bounds__(256) void mm_qkv(
    const unsigned short* __restrict__ xb,   // [4096][1536] bf16
    const unsigned short* __restrict__ wt,   // [2560][1536] bf16 (B^T)
    const float* __restrict__ rcb,           // [H*DK] fp32
    unsigned short* __restrict__ qo,         // [BH][N][64]
    unsigned short* __restrict__ ko,         // [BH][N][64]
    unsigned short* __restrict__ vo)         // [BH][N][192]
{
    __shared__ unsigned short A_lds[128 * 72];
    __shared__ unsigned short B_lds[128 * 72];
    const int tid = threadIdx.x;
    const int wave = tid >> 6, lane = tid & 63, lm = lane & 15, lg = lane >> 4;
    const int bm = blockIdx.y * 128, bn = blockIdx.x * 128;
    const int mb = (wave >> 1) * 64, nb = (wave & 1) * 64;

    floatx4 acc[4][4];
#pragma unroll
    for (int i = 0; i < 4; ++i)
#pragma unroll
        for (int j = 0; j < 4; ++j)
#pragma unroll
            for (int r = 0; r < 4; ++r) acc[i][j][r] = 0.f;

    const int srow = tid >> 3, scc = (tid & 7) * 8;
    short8 ra[4], rb[4];
#pragma unroll
    for (int p = 0; p < 4; ++p) {
        ra[p] = *(const short8*)&xb[(size_t)(bm + srow + p * 32) * kDIM + scc];
        rb[p] = *(const short8*)&wt[(size_t)(bn + srow + p * 32) * kDIM + scc];
    }

    for (int kt = 0; kt < 24; ++kt) {
        __syncthreads();
#pragma unroll
        for (int p = 0; p < 4; ++p) {
            *(short8*)&A_lds[(srow + p * 32) * 72 + scc] = ra[p];
            *(short8*)&B_lds[(srow + p * 32) * 72 + scc] = rb[p];
        }
        __syncthreads();
        if (kt < 23) {
            int k0 = (kt + 1) * 64;
#pragma unroll
            for (int p = 0; p < 4; ++p) {
                ra[p] = *(const short8*)&xb[(size_t)(bm + srow + p * 32) * kDIM + k0 + scc];
                rb[p] = *(const short8*)&wt[(size_t)(bn + srow + p * 32) * kDIM + k0 + scc];
            }
        }
#pragma unroll
        for (int ks = 0; ks < 2; ++ks) {
            short8 af[4], bf[4];
#pragma unroll
            for (int mi = 0; mi < 4; ++mi)
                af[mi] = *(const short8*)&A_lds[(mb + mi * 16 + lm) * 72 + lg * 8 + 32 * ks];
#pragma unroll
            for (int ni = 0; ni < 4; ++ni)
                bf[ni] = *(const short8*)&B_lds[(nb + ni * 16 + lm) * 72 + lg * 8 + 32 * ks];
#pragma unroll
            for (int mi = 0; mi < 4; ++mi)
#pragma unroll
                for (int ni = 0; ni < 4; ++ni)
                    acc[mi][ni] = __builtin_amdgcn_mfma_f32_16x16x32_bf16(
                        af[mi], bf[ni], acc[mi][ni], 0, 0, 0);
        }
    }

#pragma unroll
    for (int mi = 0; mi < 4; ++mi)
#pragma unroll
        for (int ni = 0; ni < 4; ++ni)
#pragma unroll
            for (int r = 0; r < 4; ++r) {
                int row = bm + mb + mi * 16 + lg * 4 + r;
                int b = row >> 11, i = row & 2047;
                int col = bn + nb + ni * 16 + lm;
                float v = acc[mi][ni][r];
                if (bn < 512) {
                    int h = col >> 6, d = col & 63;
                    qo[((size_t)(b * 8 + h) * kN + i) * kDK + d] =
                        f2b((v * kScale + rcb[h * 64 + d]) * kLog2e);
                } else if (bn < 1024) {
                    int c2 = col - 512, h = c2 >> 6, d = c2 & 63;
                    ko[((size_t)(b * 8 + h) * kN + i) * kDK + d] = f2b(v);
                } else {
                    int c2 = col - 1024, h = c2 / 192, d = c2 - h * 192;
                    vo[((size_t)(b * 8 + h) * kN + i) * kDV + d] = f2b(v);
                }
            }
}

// ---------------------------------------------------------------------------
// V transpose: [bh][i][192] -> [bh][192][i]  (bf16)
// ---------------------------------------------------------------------------
__global__ __launch_bounds__(256) void vtrans(
    const unsigned short* __restrict__ vw, unsigned short* __restrict__ vt)
{
    __shared__ unsigned short Ts[32][33];
    const int tx = threadIdx.x & 31, ty = threadIdx.x >> 5;
    const int i0 = blockIdx.x * 32, d0 = blockIdx.y * 32, bh = blockIdx.z;
#pragma unroll
    for (int p = 0; p < 4; ++p)
        Ts[ty + p * 8][tx] = vw[((size_t)bh * kN + i0 + ty + p * 8) * kDV + d0 + tx];
    __syncthreads();
#pragma unroll
    for (int p = 0; p < 4; ++p)
        vt[((size_t)bh * kDV + d0 + ty + p * 8) * kN + i0 + tx] = Ts[tx][ty + p * 8];
}

// ---------------------------------------------------------------------------
// Flash attention, MFMA. 2-barrier wave-private structure + exp2 domain +
// XCD swizzle + (R6:) l-via-ones-MFMA, defer-max THR=8, cheap P pack.
// ---------------------------------------------------------------------------
__global__ __launch_bounds__(256) void flash_attn(
    const unsigned short* __restrict__ q,    // [BH][N][64] bf16 (log2e*(s*q)+rcb folded)
    const unsigned short* __restrict__ k,    // [BH][N][64] bf16
    const unsigned short* __restrict__ vt,   // [BH][192][N] bf16 (transposed)
    const float* __restrict__ crel,          // [BH][N] fp32 (log2e folded)
    unsigned short* __restrict__ ao)         // [B*N][1536] bf16
{
    __shared__ unsigned short K_lds[64 * 72];    //  9216 B
    __shared__ unsigned short V_lds[192 * 72];   // 27648 B
    __shared__ unsigned short P_lds[4 * 16 * 68];//  8704 B (wave-private slabs)

    const int tid = threadIdx.x;
    const int wave = tid >> 6, lane = tid & 63, lm = lane & 15, lg = lane >> 4;
    // XCD swizzle: 2 bh per XCD (K/V working set 2MB fits 4MB XCD-L2)
    const int id = blockIdx.x;
    const int rem = id >> 3;
    const int bh = (id & 7) * 2 + (rem >> 5);
    const int i0 = (rem & 31) * 64;

    short8 qA[2];
    {
        const size_t qb = ((size_t)bh * kN + i0 + wave * 16 + lm) * kDK + lg * 8;
        qA[0] = *(const short8*)&q[qb];
        qA[1] = *(const short8*)&q[qb + 32];
    }
    // per-lane rel coefficients for rows lg*4+r
    float cR[4], gici[4];
#pragma unroll
    for (int r = 0; r < 4; ++r) {
        const int row = wave * 16 + lg * 4 + r;
        cR[r]   = crel[(size_t)bh * kN + i0 + row];
        gici[r] = (float)(i0 + row) * cR[r];
    }

    floatx4 o4[12];
#pragma unroll
    for (int nd = 0; nd < 12; ++nd)
#pragma unroll
        for (int r = 0; r < 4; ++r) o4[nd][r] = 0.f;
    floatx4 lacc;
#pragma unroll
    for (int r = 0; r < 4; ++r) lacc[r] = 0.f;
    float m_[4] = {-INFINITY, -INFINITY, -INFINITY, -INFINITY};

    const unsigned short* kb = k + (size_t)bh * kN * kDK;
    const unsigned short* vb = vt + (size_t)bh * kDV * kN;
    const int pbase = wave * 16 * 68;
    const int srow = tid >> 3, scol = (tid & 7) * 8;

    short8 ones;   // 1.0 bf16 broadcast (l = P @ ones via matrix pipe)
#pragma unroll
    for (int u = 0; u < 8; ++u) ones[u] = (short)0x3F80;

    for (int t = 0; t < 32; ++t) {
        const int j0 = t * 64;
        __syncthreads();   // (1) prev tile fully consumed
#pragma unroll
        for (int p = 0; p < 2; ++p)
            *(short8*)&K_lds[(srow + p * 32) * 72 + scol] =
                *(const short8*)&kb[(size_t)(j0 + srow + p * 32) * kDK + scol];
#pragma unroll
        for (int p = 0; p < 6; ++p)
            *(short8*)&V_lds[(srow + p * 32) * 72 + scol] =
                *(const short8*)&vb[(size_t)(srow + p * 32) * kN + j0 + scol];
        __syncthreads();   // (2) staged

        // S = Q K^T for this wave's 16 q-rows
        floatx4 s4[4];
#pragma unroll
        for (int st = 0; st < 4; ++st) {
#pragma unroll
            for (int r = 0; r < 4; ++r) s4[st][r] = 0.f;
#pragma unroll
            for (int ks = 0; ks < 2; ++ks) {
                short8 kf = *(const short8*)&K_lds[(st * 16 + lm) * 72 + lg * 8 + 32 * ks];
                s4[st] = __builtin_amdgcn_mfma_f32_16x16x32_bf16(qA[ks], kf, s4[st], 0, 0, 0);
            }
        }

        // rel term + per-lane local max
        float sv[4][4];    // [st][r]
        float lmax[4];
#pragma unroll
        for (int r = 0; r < 4; ++r) lmax[r] = -INFINITY;
#pragma unroll
        for (int st = 0; st < 4; ++st) {
            const float jf = (float)(j0 + st * 16 + lm);
#pragma unroll
            for (int r = 0; r < 4; ++r) {
                float v = fmaf(jf, cR[r], s4[st][r] - gici[r]);
                sv[st][r] = v;
                lmax[r] = fmaxf(lmax[r], v);
            }
        }
        // defer-max test (wave-uniform branch): skip reduce+rescale if stable
        bool ok = (lmax[0] <= m_[0] + 8.f) && (lmax[1] <= m_[1] + 8.f) &&
                  (lmax[2] <= m_[2] + 8.f) && (lmax[3] <= m_[3] + 8.f);
        if (!__all(ok)) {
#pragma unroll
            for (int r = 0; r < 4; ++r) {
                float mx = lmax[r];
                mx = fmaxf(mx, __shfl_xor(mx, 1, 64));
                mx = fmaxf(mx, __shfl_xor(mx, 2, 64));
                mx = fmaxf(mx, __shfl_xor(mx, 4, 64));
                mx = fmaxf(mx, __shfl_xor(mx, 8, 64));
                float mnew = fmaxf(m_[r], mx);
                float alpha = exp2f(m_[r] - mnew);
                m_[r] = mnew;
                lacc[r] *= alpha;
#pragma unroll
                for (int nd = 0; nd < 12; ++nd) o4[nd][r] *= alpha;
            }
        }
        // P = exp2(sv - m) -> wave-private LDS (bf16, cheap pack)
#pragma unroll
        for (int st = 0; st < 4; ++st)
#pragma unroll
            for (int r = 0; r < 4; ++r)
                P_lds[pbase + (lg * 4 + r) * 68 + st * 16 + lm] =
                    f2b_fast(exp2f(sv[st][r] - m_[r]));

        // O += P V ; l += P @ ones (matrix pipe does the row-sum)
        short8 pa[2];
        pa[0] = *(const short8*)&P_lds[pbase + lm * 68 + lg * 8];
        pa[1] = *(const short8*)&P_lds[pbase + lm * 68 + lg * 8 + 32];
        lacc = __builtin_amdgcn_mfma_f32_16x16x32_bf16(pa[0], ones, lacc, 0, 0, 0);
        lacc = __builtin_amdgcn_mfma_f32_16x16x32_bf16(pa[1], ones, lacc, 0, 0, 0);
#pragma unroll
        for (int nd = 0; nd < 12; ++nd) {
#pragma unroll
            for (int ks = 0; ks < 2; ++ks) {
                short8 vf = *(const short8*)&V_lds[(nd * 16 + lm) * 72 + lg * 8 + 32 * ks];
                o4[nd] = __builtin_amdgcn_mfma_f32_16x16x32_bf16(pa[ks], vf, o4[nd], 0, 0, 0);
            }
        }
    }

    // epilogue: ao[b, i, h*192 + d] ; l is lane-local (all cols identical)
    const int b = bh >> 3, h = bh & 7;
#pragma unroll
    for (int r = 0; r < 4; ++r) {
        float inv = 1.f / lacc[r];
        size_t rowbase = ((size_t)b * kN + i0 + wave * 16 + lg * 4 + r) * (size_t)kHDV
                         + h * kDV;
#pragma unroll
        for (int nd = 0; nd < 12; ++nd)
            ao[rowbase + nd * 16 + lm] = f2b(o4[nd][r] * inv);
    }
}

// ---------------------------------------------------------------------------
// out = aw(bf16) @ Wo + bo  (MFMA), fp32 out
// ---------------------------------------------------------------------------
__global__ __launch_bounds__(256) void mm_out(
    const unsigned short* __restrict__ aw,   // [4096][1536] bf16
    const unsigned short* __restrict__ wot,  // [1536][1536] bf16 (B^T)
    const float* __restrict__ bias,
    float* __restrict__ out)                 // [4096][1536] fp32
{
    __shared__ unsigned short A_lds[128 * 72];
    __shared__ unsigned short B_lds[128 * 72];
    const int tid = threadIdx.x;
    const int wave = tid >> 6, lane = tid & 63, lm = lane & 15, lg = lane >> 4;
    const int bm = blockIdx.y * 128, bn = blockIdx.x * 128;
    const int mb = (wave >> 1) * 64, nb = (wave & 1) * 64;

    floatx4 acc[4][4];
#pragma unroll
    for (int i = 0; i < 4; ++i)
#pragma unroll
        for (int j = 0; j < 4; ++j)
#pragma unroll
            for (int r = 0; r < 4; ++r) acc[i][j][r] = 0.f;

    const int srow = tid >> 3, scc = (tid & 7) * 8;
    short8 ra[4], rb[4];
#pragma unroll
    for (int p = 0; p < 4; ++p) {
        ra[p] = *(const short8*)&aw[(size_t)(bm + srow + p * 32) * kDIM + scc];
        rb[p] = *(const short8*)&wot[(size_t)(bn + srow + p * 32) * kDIM + scc];
    }

    for (int kt = 0; kt < 24; ++kt) {
        __syncthreads();
#pragma unroll
        for (int p = 0; p < 4; ++p) {
            *(short8*)&A_lds[(srow + p * 32) * 72 + scc] = ra[p];
            *(short8*)&B_lds[(srow + p * 32) * 72 + scc] = rb[p];
        }
        __syncthreads();
        if (kt < 23) {
            int k0 = (kt + 1) * 64;
#pragma unroll
            for (int p = 0; p < 4; ++p) {
                ra[p] = *(const short8*)&aw[(size_t)(bm + srow + p * 32) * kDIM + k0 + scc];
                rb[p] = *(const short8*)&wot[(size_t)(bn + srow + p * 32) * kDIM + k0 + scc];
            }
        }
#pragma unroll
        for (int ks = 0; ks < 2; ++ks) {
            short8 af[4], bf[4];
#pragma unroll
            for (int mi = 0; mi < 4; ++mi)
                af[mi] = *(const short8*)&A_lds[(mb + mi * 16 + lm) * 72 + lg * 8 + 32 * ks];
#pragma unroll
            for (int ni = 0; ni < 4; ++ni)
                bf[ni] = *(const short8*)&B_lds[(nb + ni * 16 + lm) * 72 + lg * 8 + 32 * ks];
#pragma unroll
            for (int mi = 0; mi < 4; ++mi)
#pragma unroll
                for (int ni = 0; ni < 4; ++ni)
                    acc[mi][ni] = __builtin_amdgcn_mfma_f32_16x16x32_bf16(
                        af[mi], bf[ni], acc[mi][ni], 0, 0, 0);
        }
    }

#pragma unroll
    for (int mi = 0; mi < 4; ++mi)
#pragma unroll
        for (int ni = 0; ni < 4; ++ni)
#pragma unroll
            for (int r = 0; r < 4; ++r) {
                int row = bm + mb + mi * 16 + lg * 4 + r;
                int col = bn + nb + ni * 16 + lm;
                out[(size_t)row * kDIM + col] = acc[mi][ni][r] + bias[col];
            }
}

// ---------------------------------------------------------------------------
extern "C" void kernel_launch(void* const* d_in, const int* in_sizes, int n_in,
                              void* d_out, int out_size, void* d_ws, size_t ws_size,
                              hipStream_t stream)
{
    const float* x    = (const float*)d_in[0];
    const float* Wq   = (const float*)d_in[1];
    const float* Wk   = (const float*)d_in[2];
    const float* Wv   = (const float*)d_in[3];
    const float* Wrel = (const float*)d_in[4];
    const float* Wo   = (const float*)d_in[5];
    const float* bo   = (const float*)d_in[6];
    const float* rcb  = (const float*)d_in[7];
    const float* rpb  = (const float*)d_in[8];
    float* out = (float*)d_out;

    char* w = (char*)d_ws;
    unsigned short* xb  = (unsigned short*)(w);              // 12,582,912 B (later: vt)
    unsigned short* wt  = (unsigned short*)(w + 12582912);   //  7,864,320 B (later: Wot)
    unsigned short* qw  = (unsigned short*)(w + 20447232);   //  4,194,304 B
    unsigned short* kw  = (unsigned short*)(w + 24641536);   //  4,194,304 B
    unsigned short* vw  = (unsigned short*)(w + 28835840);   // 12,582,912 B (later: aw)
    float*          cw  = (float*)(w + 41418752);            //    131,072 B
    float*          wcm = (float*)(w + 41549824);            //     49,184 B
    unsigned short* vtp = xb;
    unsigned short* awp = vw;
    unsigned short* wot = wt;

    { dim3 g(48, 16);  conv_w<<<g, 256, 0, stream>>>(Wq, wt,               512); }
    { dim3 g(48, 16);  conv_w<<<g, 256, 0, stream>>>(Wk, wt + 512  * 1536, 512); }
    { dim3 g(48, 48);  conv_w<<<g, 256, 0, stream>>>(Wv, wt + 1024 * 1536, 1536); }
    conv_x<<<6144, 256, 0, stream>>>(x, xb);
    wcm_pre<<<49, 256, 0, stream>>>(Wq, Wrel, rpb, wcm);
    c_gemm<<<1024, 256, 0, stream>>>(x, wcm, cw);

    { dim3 g(20, 32); mm_qkv<<<g, 256, 0, stream>>>(xb, wt, rcb, qw, kw, vw); }

    { dim3 g(48, 48); conv_w<<<g, 256, 0, stream>>>(Wo, wot, 1536); }
    { dim3 g(64, 6, 16); vtrans<<<g, 256, 0, stream>>>(vw, vtp); }

    flash_attn<<<512, 256, 0, stream>>>(qw, kw, vtp, cw, awp);

    { dim3 g(12, 32); mm_out<<<g, 256, 0, stream>>>(awp, wot, bo, out); }
}